// Round 11
// baseline (501.429 us; speedup 1.0000x reference)
//
#include <hip/hip_runtime.h>

typedef float  f32x4 __attribute__((ext_vector_type(4)));
typedef short  s16x8 __attribute__((ext_vector_type(8)));
typedef short  s16x4 __attribute__((ext_vector_type(4)));
typedef unsigned short u16;

struct PtrQuad { const float* p[4]; };

// ---------------- db4 filters ----------------
__constant__ float c_lo[8] = {-0.010597401784997278f, 0.032883011666982945f,
                              0.030841381835986965f, -0.18703481171888114f,
                              -0.02798376941698385f, 0.6308807679295904f,
                              0.7148465705525415f,  0.23037781330885523f};
__constant__ float c_hi[8] = {-0.23037781330885523f, 0.7148465705525415f,
                              -0.6308807679295904f, -0.02798376941698385f,
                              0.18703481171888114f, 0.030841381835986965f,
                              -0.032883011666982945f, -0.010597401784997278f};

__device__ __forceinline__ u16 f2bf(float f) {
    unsigned u = __float_as_uint(f);
    u += 0x7fffu + ((u >> 16) & 1u);
    return (u16)(u >> 16);
}
__device__ __forceinline__ float bf2f(u16 h) {
    return __uint_as_float(((unsigned)h) << 16);
}
__device__ __forceinline__ int lds_chunk(int row, int g) {
    return row * 4 + (g ^ ((row >> 1) & 3));
}
// async 16B global->LDS; LDS dest = wave-uniform base + lane*16 (linear).
__device__ __forceinline__ void gload16(void* lds, const void* g) {
    __builtin_amdgcn_global_load_lds(
        (__attribute__((address_space(1))) const void*)g,
        (__attribute__((address_space(3))) void*)lds,
        16, 0, 0);
}
// depth-2 counted-vmcnt wait (T4)
__device__ __forceinline__ void pipe_wait2(int t, int nt) {
    if (t + 1 < nt) asm volatile("s_waitcnt vmcnt(4)" ::: "memory");
    else            asm volatile("s_waitcnt vmcnt(0)" ::: "memory");
    __builtin_amdgcn_s_barrier();
    __builtin_amdgcn_sched_barrier(0);
}
__device__ __forceinline__ void pipe_endbar() {
    __builtin_amdgcn_sched_barrier(0);
    __builtin_amdgcn_s_barrier();
}

// ================= generic NT MFMA GEMM (conv1x1), depth-2 pipeline =================
__global__ __launch_bounds__(256) void gemm_nt_k(
    const u16* __restrict__ A, long aB, int lda,
    const u16* __restrict__ B, long bB, int ldb,
    int K,
    u16* __restrict__ D, long dB, int dj,
    const float* __restrict__ bias)
{
    __shared__ s16x8 As[2 * 512];
    __shared__ s16x8 Bs[2 * 512];
    int flat = blockIdx.x + 8 * (blockIdx.y + 4 * blockIdx.z);
    int swz = (flat & 7) * 256 + (flat >> 3);
    const int j0 = (swz & 7) * 128;
    const int i0 = ((swz >> 3) & 3) * 128;
    const long bb = swz >> 5;
    const u16* Ab = A + bb * aB;
    const u16* Bb = B + bb * bB;
    const int tid = threadIdx.x;
    const int srow = tid >> 2, sg = tid & 3;
    const int ssg = sg ^ ((srow >> 1) & 3);
    const int l = tid & 63, w = tid >> 6;
    const int wi = (w >> 1) * 64, wj = (w & 1) * 64;
    const int lr = l & 15, lg = l >> 4;
    const long aoff0 = (long)(i0 + srow) * lda + ssg * 8;
    const long aoff1 = (long)(i0 + srow + 64) * lda + ssg * 8;
    const long boff0 = (long)(j0 + srow) * ldb + ssg * 8;
    const long boff1 = (long)(j0 + srow + 64) * ldb + ssg * 8;
    const int nt = K >> 5;
    auto stage = [&](int buf, int t) {
        const int k0 = t << 5;
        char* a0 = (char*)As + buf * 8192 + w * 1024;
        char* b0 = (char*)Bs + buf * 8192 + w * 1024;
        gload16(a0, Ab + aoff0 + k0);
        gload16(a0 + 4096, Ab + aoff1 + k0);
        gload16(b0, Bb + boff0 + k0);
        gload16(b0 + 4096, Bb + boff1 + k0);
    };
    f32x4 acc[4][4] = {};
    stage(0, 0);
    for (int t = 0; t < nt; ++t) {
        const int cur = t & 1;
        if (t + 1 < nt) stage(cur ^ 1, t + 1);
        pipe_wait2(t, nt);
        s16x8 af[4], bf[4];
        #pragma unroll
        for (int f = 0; f < 4; ++f) {
            af[f] = As[cur * 512 + lds_chunk(wi + f * 16 + lr, lg)];
            bf[f] = Bs[cur * 512 + lds_chunk(wj + f * 16 + lr, lg)];
        }
        __builtin_amdgcn_s_setprio(1);
        #pragma unroll
        for (int fi = 0; fi < 4; ++fi)
            #pragma unroll
            for (int fj = 0; fj < 4; ++fj)
                acc[fi][fj] = __builtin_amdgcn_mfma_f32_16x16x32_bf16(af[fi], bf[fj], acc[fi][fj], 0, 0, 0);
        __builtin_amdgcn_s_setprio(0);
        pipe_endbar();
    }
    u16* Db = D + bb * dB;
    #pragma unroll
    for (int fi = 0; fi < 4; ++fi) {
        const int i = i0 + wi + fi * 16 + lg * 4;
        float b0 = 0, b1 = 0, b2v = 0, b3 = 0;
        if (bias) { b0 = bias[i]; b1 = bias[i + 1]; b2v = bias[i + 2]; b3 = bias[i + 3]; }
        #pragma unroll
        for (int fj = 0; fj < 4; ++fj) {
            const int j = j0 + wj + fj * 16 + lr;
            f32x4 d = acc[fi][fj];
            s16x4 o;
            o[0] = (short)f2bf(d[0] + b0); o[1] = (short)f2bf(d[1] + b1);
            o[2] = (short)f2bf(d[2] + b2v); o[3] = (short)f2bf(d[3] + b3);
            *(s16x4*)(Db + (long)j * dj + i) = o;
        }
    }
}

// ================= branch conv: chunk-major, B window staged once per chunk =================
__global__ __launch_bounds__(256) void gemm_branch4_k(
    const u16* __restrict__ WpAll,
    const u16* __restrict__ H,
    u16* __restrict__ Y,
    const u16* __restrict__ zbuf,
    float* __restrict__ part)
{
    __shared__ char Alds[2 * 8192];
    __shared__ char Blds[2 * 12288];
    __shared__ float sred[2][128];
    __shared__ float qred[2][128];
    int flat = blockIdx.x + 8 * (blockIdx.y + 4 * blockIdx.z);
    int swz = (flat & 7) * 256 + (flat >> 3);
    const int jblk = swz & 7;
    const int br = (swz >> 3) & 3;
    const long bb = swz >> 5;
    const int j0 = jblk * 128;
    const int taps = 3 + 2 * br;
    const int pad = 1 + br;
    const u16* Wpb = WpAll + (long)(br * br + 2 * br) * 16384;
    const u16* Hb = H + bb * 524288 + 128 * br;
    const int tid = threadIdx.x;
    const int l = tid & 63, w = tid >> 6;
    const int wi = (w >> 1) * 64, wj = (w & 1) * 64;
    const int lr = l & 15, lg = l >> 4;
    const int lrow = l >> 2, lq = l & 3;
    const int ssg2 = lq ^ ((lrow >> 1) & 3);
    const int lda = taps * 128;

    auto stageA = [&](int buf, int c, int t) {
        char* dst = Alds + buf * 8192 + w * 2048;
        #pragma unroll
        for (int q = 0; q < 2; ++q) {
            int row = w * 32 + q * 16 + lrow;
            gload16(dst + q * 1024,
                    Wpb + (long)row * lda + t * 128 + c * 32 + ssg2 * 8);
        }
    };
    auto stageB = [&](int buf, int c) {
        char* dst = Blds + buf * 12288 + w * 3072;
        #pragma unroll
        for (int q = 0; q < 3; ++q) {
            int winrow = w * 48 + q * 16 + lrow;
            int grow = j0 - 32 + winrow;
            const u16* src = (grow >= 0 && grow < 1024)
                           ? (Hb + (long)grow * 512 + c * 32 + ssg2 * 8) : zbuf;
            gload16(dst + q * 1024, src);
        }
    };

    f32x4 acc[4][4] = {};
    int abuf = 0, bbuf = 0;
    stageB(0, 0);
    stageA(0, 0, 0);
    for (int c = 0; c < 4; ++c) {
        for (int t = 0; t < taps; ++t) {
            if (t + 1 < taps) {
                stageA(abuf ^ 1, c, t + 1);
                asm volatile("s_waitcnt vmcnt(2)" ::: "memory");
            } else if (c + 1 < 4) {
                stageB(bbuf ^ 1, c + 1);
                stageA(abuf ^ 1, c + 1, 0);
                asm volatile("s_waitcnt vmcnt(5)" ::: "memory");
            } else {
                asm volatile("s_waitcnt vmcnt(0)" ::: "memory");
            }
            __builtin_amdgcn_s_barrier();
            __builtin_amdgcn_sched_barrier(0);
            const char* Al = Alds + abuf * 8192;
            const char* Bl = Blds + bbuf * 12288;
            const int shift2 = t - pad + 32;
            s16x8 af[4], bf[4];
            #pragma unroll
            for (int f = 0; f < 4; ++f) {
                int arow = wi + f * 16 + lr;
                af[f] = *(const s16x8*)(Al + arow * 64 + (lg ^ ((arow >> 1) & 3)) * 16);
                int brow = wj + f * 16 + lr + shift2;
                bf[f] = *(const s16x8*)(Bl + brow * 64 + (lg ^ ((brow >> 1) & 3)) * 16);
            }
            __builtin_amdgcn_s_setprio(1);
            #pragma unroll
            for (int fi = 0; fi < 4; ++fi)
                #pragma unroll
                for (int fj = 0; fj < 4; ++fj)
                    acc[fi][fj] = __builtin_amdgcn_mfma_f32_16x16x32_bf16(af[fi], bf[fj], acc[fi][fj], 0, 0, 0);
            __builtin_amdgcn_s_setprio(0);
            __builtin_amdgcn_sched_barrier(0);
            __builtin_amdgcn_s_barrier();
            abuf ^= 1;
            if (t == taps - 1) bbuf ^= 1;
        }
    }
    u16* Db = Y + bb * 524288 + 128 * br;
    #pragma unroll
    for (int fi = 0; fi < 4; ++fi) {
        const int i = wi + fi * 16 + lg * 4;
        #pragma unroll
        for (int fj = 0; fj < 4; ++fj) {
            const int j = j0 + wj + fj * 16 + lr;
            f32x4 d = acc[fi][fj];
            s16x4 o;
            o[0] = (short)f2bf(d[0]); o[1] = (short)f2bf(d[1]);
            o[2] = (short)f2bf(d[2]); o[3] = (short)f2bf(d[3]);
            *(s16x4*)(Db + (long)j * 512 + i) = o;
        }
    }
    // ---- BN partial stats ----
    float sv[16], qv[16];
    #pragma unroll
    for (int fi = 0; fi < 4; ++fi)
        #pragma unroll
        for (int e = 0; e < 4; ++e) {
            float s = 0.f, q = 0.f;
            #pragma unroll
            for (int fj = 0; fj < 4; ++fj) { float d = acc[fi][fj][e]; s += d; q += d * d; }
            sv[fi * 4 + e] = s; qv[fi * 4 + e] = q;
        }
    #pragma unroll
    for (int m = 1; m < 16; m <<= 1) {
        #pragma unroll
        for (int r = 0; r < 16; ++r) {
            sv[r] += __shfl_xor(sv[r], m, 64);
            qv[r] += __shfl_xor(qv[r], m, 64);
        }
    }
    __syncthreads();
    if (lr == 0) {
        #pragma unroll
        for (int r = 0; r < 16; ++r) {
            int co = wi + (r >> 2) * 16 + lg * 4 + (r & 3);
            sred[w & 1][co] = sv[r];
            qred[w & 1][co] = qv[r];
        }
    }
    __syncthreads();
    if (tid < 128) {
        long blk = (long)br * 512 + bb * 8 + jblk;
        part[blk * 256 + tid]       = sred[0][tid] + sred[1][tid];
        part[blk * 256 + 128 + tid] = qred[0][tid] + qred[1][tid];
    }
}

// ================= Z = MS . Ybn (banded): Z[n][c] =================
// A = YbnT (c rows, m-major), B = MS (n rows, m-major), band m in [j0-32, j0+160)
__global__ __launch_bounds__(256) void gemm_z_k(
    const u16* __restrict__ YT,
    const u16* __restrict__ MS,
    u16* __restrict__ Z)
{
    __shared__ s16x8 As[2 * 512];
    __shared__ s16x8 Bs[2 * 512];
    int flat = blockIdx.x + 8 * (blockIdx.y + 4 * blockIdx.z);
    int swz = (flat & 7) * 256 + (flat >> 3);
    const int j0 = (swz & 7) * 128;        // n tile
    const int i0 = ((swz >> 3) & 3) * 128; // c tile
    const long bb = swz >> 5;
    const u16* Ab = YT + bb * 524288;
    const int tid = threadIdx.x;
    const int srow = tid >> 2, sg = tid & 3;
    const int ssg = sg ^ ((srow >> 1) & 3);
    const int l = tid & 63, w = tid >> 6;
    const int wi = (w >> 1) * 64, wj = (w & 1) * 64;
    const int lr = l & 15, lg = l >> 4;
    const int klo = (j0 - 32) > 0 ? (j0 - 32) : 0;
    const int khi = (j0 + 160) < 1024 ? (j0 + 160) : 1024;
    const int nt = (khi - klo) >> 5;
    auto stage = [&](int buf, int t) {
        const int k0 = klo + (t << 5);
        char* a0 = (char*)As + buf * 8192 + w * 1024;
        char* b0 = (char*)Bs + buf * 8192 + w * 1024;
        gload16(a0, Ab + (long)(i0 + srow) * 1024 + k0 + ssg * 8);
        gload16(a0 + 4096, Ab + (long)(i0 + srow + 64) * 1024 + k0 + ssg * 8);
        gload16(b0, MS + (long)(j0 + srow) * 1024 + k0 + ssg * 8);
        gload16(b0 + 4096, MS + (long)(j0 + srow + 64) * 1024 + k0 + ssg * 8);
    };
    f32x4 acc[4][4] = {};
    stage(0, 0);
    for (int t = 0; t < nt; ++t) {
        const int cur = t & 1;
        if (t + 1 < nt) stage(cur ^ 1, t + 1);
        pipe_wait2(t, nt);
        s16x8 af[4], bf[4];
        #pragma unroll
        for (int f = 0; f < 4; ++f) {
            af[f] = As[cur * 512 + lds_chunk(wi + f * 16 + lr, lg)];
            bf[f] = Bs[cur * 512 + lds_chunk(wj + f * 16 + lr, lg)];
        }
        __builtin_amdgcn_s_setprio(1);
        #pragma unroll
        for (int fi = 0; fi < 4; ++fi)
            #pragma unroll
            for (int fj = 0; fj < 4; ++fj)
                acc[fi][fj] = __builtin_amdgcn_mfma_f32_16x16x32_bf16(af[fi], bf[fj], acc[fi][fj], 0, 0, 0);
        __builtin_amdgcn_s_setprio(0);
        pipe_endbar();
    }
    u16* Db = Z + bb * 524288;
    #pragma unroll
    for (int fi = 0; fi < 4; ++fi) {
        const int i = i0 + wi + fi * 16 + lg * 4;   // c
        #pragma unroll
        for (int fj = 0; fj < 4; ++fj) {
            const int j = j0 + wj + fj * 16 + lr;   // n
            f32x4 d = acc[fi][fj];
            s16x4 o;
            o[0] = (short)f2bf(d[0]); o[1] = (short)f2bf(d[1]);
            o[2] = (short)f2bf(d[2]); o[3] = (short)f2bf(d[3]);
            *(s16x4*)(Db + (long)j * 512 + i) = o;   // Z[n][c]
        }
    }
}

// ================= final GEMM: out = UD.Z + UL.Ybn + b2 + x (dual pass, f32 out) =================
// pass0: A = Z (n rows, c-major), B = UD; pass1: A = Ybn, B = UL
__global__ __launch_bounds__(256) void gemm_out_k(
    const u16* __restrict__ Z, const u16* __restrict__ Ybn,
    const u16* __restrict__ UDUL,
    const float* __restrict__ b2, const float* __restrict__ X,
    float* __restrict__ OUT)
{
    __shared__ s16x8 As[2 * 512];
    __shared__ s16x8 Bs[2 * 512];
    int flat = blockIdx.x + 4 * (blockIdx.y + 8 * blockIdx.z);
    int swz = (flat & 7) * 256 + (flat >> 3);
    const int j0 = (swz & 3) * 128;          // co tile
    const int i0 = ((swz >> 2) & 7) * 128;   // n tile
    const long bb = swz >> 5;
    const int tid = threadIdx.x;
    const int srow = tid >> 2, sg = tid & 3;
    const int ssg = sg ^ ((srow >> 1) & 3);
    const int l = tid & 63, w = tid >> 6;
    const int wi = (w >> 1) * 64, wj = (w & 1) * 64;
    const int lr = l & 15, lg = l >> 4;
    const u16* A0 = Z + bb * 524288;
    const u16* A1 = Ybn + bb * 524288;
    const u16* B0 = UDUL;               // UD rows [0,512)
    const u16* B1 = UDUL + 262144;      // UL rows [512,1024)
    const int nt = 32;
    auto stage = [&](int buf, int t) {
        const int pass = t >> 4;
        const int k0 = (t & 15) << 5;
        const u16* A = pass ? A1 : A0;
        const u16* B = pass ? B1 : B0;
        char* a0 = (char*)As + buf * 8192 + w * 1024;
        char* b0 = (char*)Bs + buf * 8192 + w * 1024;
        gload16(a0, A + (long)(i0 + srow) * 512 + k0 + ssg * 8);
        gload16(a0 + 4096, A + (long)(i0 + srow + 64) * 512 + k0 + ssg * 8);
        gload16(b0, B + (long)(j0 + srow) * 512 + k0 + ssg * 8);
        gload16(b0 + 4096, B + (long)(j0 + srow + 64) * 512 + k0 + ssg * 8);
    };
    f32x4 acc[4][4] = {};
    stage(0, 0);
    for (int t = 0; t < nt; ++t) {
        const int cur = t & 1;
        if (t + 1 < nt) stage(cur ^ 1, t + 1);
        pipe_wait2(t, nt);
        s16x8 af[4], bf[4];
        #pragma unroll
        for (int f = 0; f < 4; ++f) {
            af[f] = As[cur * 512 + lds_chunk(wi + f * 16 + lr, lg)];
            bf[f] = Bs[cur * 512 + lds_chunk(wj + f * 16 + lr, lg)];
        }
        __builtin_amdgcn_s_setprio(1);
        #pragma unroll
        for (int fi = 0; fi < 4; ++fi)
            #pragma unroll
            for (int fj = 0; fj < 4; ++fj)
                acc[fi][fj] = __builtin_amdgcn_mfma_f32_16x16x32_bf16(af[fi], bf[fj], acc[fi][fj], 0, 0, 0);
        __builtin_amdgcn_s_setprio(0);
        pipe_endbar();
    }
    float* Ob = OUT + bb * 524288;
    const float* Xb = X + bb * 524288;
    #pragma unroll
    for (int fi = 0; fi < 4; ++fi) {
        const int i = i0 + wi + fi * 16 + lg * 4;    // n
        #pragma unroll
        for (int fj = 0; fj < 4; ++fj) {
            const int j = j0 + wj + fj * 16 + lr;    // co
            const long a = (long)j * 1024 + i;
            f32x4 d = acc[fi][fj];
            const float bj = b2[j];
            f32x4 xv = *(const f32x4*)(Xb + a);
            f32x4 o;
            o[0] = d[0] + bj + xv[0]; o[1] = d[1] + bj + xv[1];
            o[2] = d[2] + bj + xv[2]; o[3] = d[3] + bj + xv[3];
            *(f32x4*)(Ob + a) = o;
        }
    }
}

// ================= build wavelet operator MS =================
__global__ __launch_bounds__(256) void build_M_k(u16* __restrict__ MS)
{
    __shared__ float a1[515], d1[515], a2[261], d2[261], sa1[515];
    const int r = blockIdx.x;
    const int t = threadIdx.x;
    for (int m = t; m < 515; m += 256) {
        float sa = 0.f, sd = 0.f;
        #pragma unroll
        for (int j = 0; j < 8; ++j) {
            int tt = 2 * m + 1 - j;
            tt = (tt < 0) ? (-tt - 1) : tt;
            tt = (tt >= 1024) ? (2047 - tt) : tt;
            if (tt == r) { sa += c_lo[j]; sd += c_hi[j]; }
        }
        a1[m] = sa; d1[m] = sd;
    }
    __syncthreads();
    for (int m = t; m < 261; m += 256) {
        float sa = 0.f, sd = 0.f;
        #pragma unroll
        for (int j = 0; j < 8; ++j) {
            int tt = 2 * m + 1 - j;
            tt = (tt < 0) ? (-tt - 1) : tt;
            tt = (tt >= 515) ? (1029 - tt) : tt;
            float v = a1[tt];
            sa += v * c_lo[j]; sd += v * c_hi[j];
        }
        a2[m] = sa; d2[m] = sd;
    }
    __syncthreads();
    for (int m = t; m < 515; m += 256) {
        float ss = 0.f;
        #pragma unroll
        for (int k = 0; k < 8; ++k) {
            int tt = m + k - 1;
            if (tt & 1) continue;
            int j = tt >> 1;
            if (j < 0 || j >= 261) continue;
            ss += c_hi[k] * d2[j];
        }
        sa1[m] = ss;
    }
    __syncthreads();
    for (int n = t; n < 1024; n += 256) {
        float ss = 0.f;
        #pragma unroll
        for (int k = 0; k < 8; ++k) {
            int tt = n + k - 1;
            if (tt & 1) continue;
            int j = tt >> 1;
            if (j < 0 || j >= 515) continue;
            ss += c_lo[k] * sa1[j] + c_hi[k] * d1[j];
        }
        MS[(long)n * 1024 + r] = f2bf(ss);
    }
}

// ================= packing / small kernels =================
__global__ __launch_bounds__(256) void pack_weights_k(
    const float* __restrict__ wi,
    const float* __restrict__ b1, const float* __restrict__ b2_,
    const float* __restrict__ b3, const float* __restrict__ b4,
    u16* __restrict__ Wi, u16* __restrict__ Wp)
{
    int i = blockIdx.x * 256 + threadIdx.x;
    if (i < 262144) Wi[i] = f2bf(wi[i]);
    if (i < 393216) {
        int base, taps;
        const float* s;
        if (i < 49152)       { base = 0;      taps = 3; s = b1; }
        else if (i < 131072) { base = 49152;  taps = 5; s = b2_; }
        else if (i < 245760) { base = 131072; taps = 7; s = b3; }
        else                 { base = 245760; taps = 9; s = b4; }
        int rem = i - base;
        int stride = taps * 128;
        int co = rem / stride;
        int r2 = rem - co * stride;
        int tap = r2 >> 7, ci = r2 & 127;
        Wp[i] = f2bf(s[(long)(co * 128 + ci) * taps + tap]);
    }
}

__global__ __launch_bounds__(256) void make_Ucum_k(
    const float* __restrict__ wf, const float* __restrict__ wp,
    u16* __restrict__ UDUL)
{
    int gid = blockIdx.x * 256 + threadIdx.x;   // 512*128
    int co = gid >> 7, cc = gid & 127;
    float us[4], ul[4];
    #pragma unroll
    for (int b = 0; b < 4; ++b) {
        float s = 0.f, t = 0.f;
        for (int q = 0; q < 128; ++q) {
            float f = wf[(long)co * 512 + b * 128 + q];
            s += f * wp[q * 256 + cc];
            t += f * wp[q * 256 + 128 + cc];
        }
        us[b] = s; ul[b] = t;
    }
    float suf[4], pre[4];
    float acc = 0.f;
    for (int b = 3; b >= 0; --b) { acc += us[b]; suf[b] = acc; }
    acc = 0.f;
    for (int b = 0; b < 4; ++b) { acc += ul[b]; pre[b] = acc; }
    #pragma unroll
    for (int b = 0; b < 4; ++b) {
        UDUL[(long)co * 512 + b * 128 + cc]         = f2bf(suf[b] - pre[b]);
        UDUL[(long)(512 + co) * 512 + b * 128 + cc] = f2bf(pre[b]);
    }
}

__global__ __launch_bounds__(256) void make_bias2_k(
    const float* __restrict__ wf, const float* __restrict__ bpf,
    const float* __restrict__ bfus, float* __restrict__ b2)
{
    int co = blockIdx.x * 256 + threadIdx.x;
    if (co >= 512) return;
    float s = bfus[co];
    for (int j = 0; j < 512; ++j) s += wf[(long)co * 512 + j] * bpf[j & 127];
    b2[co] = s;
}

__global__ __launch_bounds__(256) void zero_k(float* __restrict__ p, int n)
{
    int i = blockIdx.x * 256 + threadIdx.x;
    if (i < n) p[i] = 0.f;
}

// ---------------- transpose: xcl[bb][n][c] = bf16(x[bb][c][n]) ----------------
__global__ __launch_bounds__(256) void trX_k(const float* __restrict__ x, u16* __restrict__ xcl)
{
    __shared__ float sh[32][33];
    const int n0 = blockIdx.x * 32, c0 = blockIdx.y * 32;
    const long bb = blockIdx.z;
    const int tx = threadIdx.x, ty = threadIdx.y;
    const float* xb = x + bb * 524288;
    u16* ob = xcl + bb * 524288;
    #pragma unroll
    for (int k = 0; k < 4; ++k)
        sh[ty + 8 * k][tx] = xb[(long)(c0 + ty + 8 * k) * 1024 + n0 + tx];
    __syncthreads();
    #pragma unroll
    for (int k = 0; k < 4; ++k)
        ob[(long)(n0 + ty + 8 * k) * 512 + c0 + tx] = f2bf(sh[tx][ty + 8 * k]);
}

// ---------------- BN ----------------
__global__ __launch_bounds__(256) void bn_coef_k(
    const float* __restrict__ part, PtrQuad g, PtrQuad be, float* __restrict__ scsh)
{
    __shared__ float rs[256], rq[256];
    int c = blockIdx.x;              // 0..511
    int br = c >> 7, cc = c & 127;
    const float* pb = part + (long)br * 131072;
    int t = threadIdx.x;
    float s = pb[(2 * t) * 256 + cc]       + pb[(2 * t + 1) * 256 + cc];
    float q = pb[(2 * t) * 256 + 128 + cc] + pb[(2 * t + 1) * 256 + 128 + cc];
    rs[t] = s; rq[t] = q;
    __syncthreads();
    for (int off = 128; off > 0; off >>= 1) {
        if (t < off) { rs[t] += rs[t + off]; rq[t] += rq[t + off]; }
        __syncthreads();
    }
    if (t == 0) {
        float mu = rs[0] * (1.0f / 65536.0f);
        float var = rq[0] * (1.0f / 65536.0f) - mu * mu;
        float sc = g.p[br][cc] * rsqrtf(var + 1e-5f);
        scsh[c] = sc;
        scsh[512 + c] = be.p[br][cc] - mu * sc;
    }
}

// BN+ReLU in place on Y [m][c] AND write YbnT [c][m] (transposed)
__global__ __launch_bounds__(256) void bn_apply_tr_k(
    u16* __restrict__ Y, u16* __restrict__ YT, const float* __restrict__ scsh)
{
    __shared__ u16 sh[32][34];
    __shared__ float sc_[32], shf_[32];
    const int m0 = blockIdx.x * 32, c0 = blockIdx.y * 32;
    const long bb = blockIdx.z;
    const int tx = threadIdx.x, ty = threadIdx.y;   // block (32,8)
    if (ty == 0) { sc_[tx] = scsh[c0 + tx]; shf_[tx] = scsh[512 + c0 + tx]; }
    __syncthreads();
    u16* Yb = Y + bb * 524288;
    u16* Tb = YT + bb * 524288;
    #pragma unroll
    for (int k = 0; k < 4; ++k) {
        int m = m0 + ty + 8 * k;
        long a = (long)m * 512 + c0 + tx;
        float f = bf2f(Yb[a]) * sc_[tx] + shf_[tx];
        u16 o = f2bf(f > 0.f ? f : 0.f);
        Yb[a] = o;
        sh[ty + 8 * k][tx] = o;
    }
    __syncthreads();
    #pragma unroll
    for (int k = 0; k < 4; ++k)
        Tb[(long)(c0 + ty + 8 * k) * 1024 + m0 + tx] = sh[tx][ty + 8 * k];
}

// =====================================================================
extern "C" void kernel_launch(void* const* d_in, const int* in_sizes, int n_in,
                              void* d_out, int out_size, void* d_ws, size_t ws_size,
                              hipStream_t stream)
{
    const float* x      = (const float*)d_in[0];
    const float* w_init = (const float*)d_in[1];
    const float* b_init = (const float*)d_in[2];
    const float* w_pf   = (const float*)d_in[3];
    const float* b_pf   = (const float*)d_in[4];
    const float* w_fus  = (const float*)d_in[5];
    const float* b_fus  = (const float*)d_in[6];
    const float *w_b[4];
    PtrQuad g, be;
    for (int i = 0; i < 4; ++i) {
        w_b[i]  = (const float*)d_in[7 + 4 * i];
        g.p[i]  = (const float*)d_in[9 + 4 * i];
        be.p[i] = (const float*)d_in[10 + 4 * i];
    }
    float* outf = (float*)d_out;

    char* p = (char*)d_ws;
    u16* xcl   = (u16*)p;  p += 67108864;
    u16* h     = (u16*)p;  p += 67108864;
    u16* Y     = (u16*)p;  p += 67108864;
    u16* YT    = (u16*)p;  p += 67108864;
    u16* Z     = (u16*)p;  p += 67108864;
    u16* Wi    = (u16*)p;  p += 524288;
    u16* Wp    = (u16*)p;  p += 786432;
    u16* UDUL  = (u16*)p;  p += 1048576;
    u16* MrowS = (u16*)p;  p += 2097152;
    float* b2  = (float*)p; p += 2048;
    float* zbuf= (float*)p; p += 256;
    float* scsh= (float*)p; p += 4096;
    float* part= (float*)p; p += 2097152;

    // ---- prologue: weights / operators ----
    pack_weights_k<<<1536, 256, 0, stream>>>(w_init, w_b[0], w_b[1], w_b[2], w_b[3], Wi, Wp);
    make_Ucum_k<<<256, 256, 0, stream>>>(w_fus, w_pf, UDUL);
    make_bias2_k<<<2, 256, 0, stream>>>(w_fus, b_pf, b_fus, b2);
    build_M_k<<<1024, 256, 0, stream>>>(MrowS);
    zero_k<<<1, 256, 0, stream>>>(zbuf, 64);

    // ---- activations: transpose to channel-last bf16 ----
    trX_k<<<dim3(32, 16, 64), dim3(32, 8), 0, stream>>>(x, xcl);

    // ---- conv1x1: h[n][co] = Wi x + b_init ----
    gemm_nt_k<<<dim3(8, 4, 64), 256, 0, stream>>>(Wi, 0, 512, xcl, 524288, 512, 512,
                                                  h, 524288, 512, b_init);

    // ---- branches: chunk-major conv + fused BN partials ----
    gemm_branch4_k<<<dim3(8, 4, 64), 256, 0, stream>>>(Wp, h, Y, (const u16*)zbuf, part);

    // ---- BN coefficients + apply-with-transpose ----
    bn_coef_k<<<512, 256, 0, stream>>>(part, g, be, scsh);
    bn_apply_tr_k<<<dim3(32, 16, 64), dim3(32, 8), 0, stream>>>(Y, YT, scsh);

    // ---- Z[n][c] = (MS . Ybn) (banded) ----
    gemm_z_k<<<dim3(8, 4, 64), 256, 0, stream>>>(YT, MrowS, Z);

    // ---- out = UD.Z + UL.Ybn + b2 + x ----
    gemm_out_k<<<dim3(4, 8, 64), 256, 0, stream>>>(Z, Y, UDUL, b2, x, outf);
}

// Round 12
// 477.226 us; speedup vs baseline: 1.0507x; 1.0507x over previous
//
#include <hip/hip_runtime.h>

typedef float  f32x4 __attribute__((ext_vector_type(4)));
typedef short  s16x8 __attribute__((ext_vector_type(8)));
typedef short  s16x4 __attribute__((ext_vector_type(4)));
typedef unsigned short u16;

struct PtrQuad { const float* p[4]; };

// ---------------- db4 filters ----------------
__constant__ float c_lo[8] = {-0.010597401784997278f, 0.032883011666982945f,
                              0.030841381835986965f, -0.18703481171888114f,
                              -0.02798376941698385f, 0.6308807679295904f,
                              0.7148465705525415f,  0.23037781330885523f};
__constant__ float c_hi[8] = {-0.23037781330885523f, 0.7148465705525415f,
                              -0.6308807679295904f, -0.02798376941698385f,
                              0.18703481171888114f, 0.030841381835986965f,
                              -0.032883011666982945f, -0.010597401784997278f};

__device__ __forceinline__ u16 f2bf(float f) {
    unsigned u = __float_as_uint(f);
    u += 0x7fffu + ((u >> 16) & 1u);
    return (u16)(u >> 16);
}
__device__ __forceinline__ float bf2f(u16 h) {
    return __uint_as_float(((unsigned)h) << 16);
}
__device__ __forceinline__ int lds_chunk(int row, int g) {
    return row * 4 + (g ^ ((row >> 1) & 3));
}
// async 16B global->LDS; LDS dest = wave-uniform base + lane*16 (linear).
__device__ __forceinline__ void gload16(void* lds, const void* g) {
    __builtin_amdgcn_global_load_lds(
        (__attribute__((address_space(1))) const void*)g,
        (__attribute__((address_space(3))) void*)lds,
        16, 0, 0);
}
// depth-2 counted-vmcnt wait (T4)
__device__ __forceinline__ void pipe_wait2(int t, int nt) {
    if (t + 1 < nt) asm volatile("s_waitcnt vmcnt(4)" ::: "memory");
    else            asm volatile("s_waitcnt vmcnt(0)" ::: "memory");
    __builtin_amdgcn_s_barrier();
    __builtin_amdgcn_sched_barrier(0);
}
// depth-3 counted-vmcnt wait (r7-verified)
__device__ __forceinline__ void pipe_wait3(int t, int nt) {
    if (t + 2 < nt)      asm volatile("s_waitcnt vmcnt(8)" ::: "memory");
    else if (t + 1 < nt) asm volatile("s_waitcnt vmcnt(4)" ::: "memory");
    else                 asm volatile("s_waitcnt vmcnt(0)" ::: "memory");
    __builtin_amdgcn_s_barrier();
    __builtin_amdgcn_sched_barrier(0);
}
__device__ __forceinline__ void pipe_endbar() {
    __builtin_amdgcn_sched_barrier(0);
    __builtin_amdgcn_s_barrier();
}

// ================= generic NT MFMA GEMM (conv1x1), depth-2 pipeline =================
__global__ __launch_bounds__(256) void gemm_nt_k(
    const u16* __restrict__ A, long aB, int lda,
    const u16* __restrict__ B, long bB, int ldb,
    int K,
    u16* __restrict__ D, long dB, int dj,
    const float* __restrict__ bias)
{
    __shared__ s16x8 As[2 * 512];
    __shared__ s16x8 Bs[2 * 512];
    int flat = blockIdx.x + 8 * (blockIdx.y + 4 * blockIdx.z);
    int swz = (flat & 7) * 256 + (flat >> 3);
    const int j0 = (swz & 7) * 128;
    const int i0 = ((swz >> 3) & 3) * 128;
    const long bb = swz >> 5;
    const u16* Ab = A + bb * aB;
    const u16* Bb = B + bb * bB;
    const int tid = threadIdx.x;
    const int srow = tid >> 2, sg = tid & 3;
    const int ssg = sg ^ ((srow >> 1) & 3);
    const int l = tid & 63, w = tid >> 6;
    const int wi = (w >> 1) * 64, wj = (w & 1) * 64;
    const int lr = l & 15, lg = l >> 4;
    const long aoff0 = (long)(i0 + srow) * lda + ssg * 8;
    const long aoff1 = (long)(i0 + srow + 64) * lda + ssg * 8;
    const long boff0 = (long)(j0 + srow) * ldb + ssg * 8;
    const long boff1 = (long)(j0 + srow + 64) * ldb + ssg * 8;
    const int nt = K >> 5;
    auto stage = [&](int buf, int t) {
        const int k0 = t << 5;
        char* a0 = (char*)As + buf * 8192 + w * 1024;
        char* b0 = (char*)Bs + buf * 8192 + w * 1024;
        gload16(a0, Ab + aoff0 + k0);
        gload16(a0 + 4096, Ab + aoff1 + k0);
        gload16(b0, Bb + boff0 + k0);
        gload16(b0 + 4096, Bb + boff1 + k0);
    };
    f32x4 acc[4][4] = {};
    stage(0, 0);
    for (int t = 0; t < nt; ++t) {
        const int cur = t & 1;
        if (t + 1 < nt) stage(cur ^ 1, t + 1);
        pipe_wait2(t, nt);
        s16x8 af[4], bf[4];
        #pragma unroll
        for (int f = 0; f < 4; ++f) {
            af[f] = As[cur * 512 + lds_chunk(wi + f * 16 + lr, lg)];
            bf[f] = Bs[cur * 512 + lds_chunk(wj + f * 16 + lr, lg)];
        }
        __builtin_amdgcn_s_setprio(1);
        #pragma unroll
        for (int fi = 0; fi < 4; ++fi)
            #pragma unroll
            for (int fj = 0; fj < 4; ++fj)
                acc[fi][fj] = __builtin_amdgcn_mfma_f32_16x16x32_bf16(af[fi], bf[fj], acc[fi][fj], 0, 0, 0);
        __builtin_amdgcn_s_setprio(0);
        pipe_endbar();
    }
    u16* Db = D + bb * dB;
    #pragma unroll
    for (int fi = 0; fi < 4; ++fi) {
        const int i = i0 + wi + fi * 16 + lg * 4;
        float b0 = 0, b1 = 0, b2v = 0, b3 = 0;
        if (bias) { b0 = bias[i]; b1 = bias[i + 1]; b2v = bias[i + 2]; b3 = bias[i + 3]; }
        #pragma unroll
        for (int fj = 0; fj < 4; ++fj) {
            const int j = j0 + wj + fj * 16 + lr;
            f32x4 d = acc[fi][fj];
            s16x4 o;
            o[0] = (short)f2bf(d[0] + b0); o[1] = (short)f2bf(d[1] + b1);
            o[2] = (short)f2bf(d[2] + b2v); o[3] = (short)f2bf(d[3] + b3);
            *(s16x4*)(Db + (long)j * dj + i) = o;
        }
    }
}

// ================= branch conv: chunk-major, B window staged once per chunk =================
__global__ __launch_bounds__(256) void gemm_branch4_k(
    const u16* __restrict__ WpAll,
    const u16* __restrict__ H,
    u16* __restrict__ Y,
    const u16* __restrict__ zbuf,
    float* __restrict__ part)
{
    __shared__ char Alds[2 * 8192];
    __shared__ char Blds[2 * 12288];
    __shared__ float sred[2][128];
    __shared__ float qred[2][128];
    int flat = blockIdx.x + 8 * (blockIdx.y + 4 * blockIdx.z);
    int swz = (flat & 7) * 256 + (flat >> 3);
    const int jblk = swz & 7;
    const int br = (swz >> 3) & 3;
    const long bb = swz >> 5;
    const int j0 = jblk * 128;
    const int taps = 3 + 2 * br;
    const int pad = 1 + br;
    const u16* Wpb = WpAll + (long)(br * br + 2 * br) * 16384;
    const u16* Hb = H + bb * 524288 + 128 * br;
    const int tid = threadIdx.x;
    const int l = tid & 63, w = tid >> 6;
    const int wi = (w >> 1) * 64, wj = (w & 1) * 64;
    const int lr = l & 15, lg = l >> 4;
    const int lrow = l >> 2, lq = l & 3;
    const int ssg2 = lq ^ ((lrow >> 1) & 3);
    const int lda = taps * 128;

    auto stageA = [&](int buf, int c, int t) {
        char* dst = Alds + buf * 8192 + w * 2048;
        #pragma unroll
        for (int q = 0; q < 2; ++q) {
            int row = w * 32 + q * 16 + lrow;
            gload16(dst + q * 1024,
                    Wpb + (long)row * lda + t * 128 + c * 32 + ssg2 * 8);
        }
    };
    auto stageB = [&](int buf, int c) {
        char* dst = Blds + buf * 12288 + w * 3072;
        #pragma unroll
        for (int q = 0; q < 3; ++q) {
            int winrow = w * 48 + q * 16 + lrow;
            int grow = j0 - 32 + winrow;
            const u16* src = (grow >= 0 && grow < 1024)
                           ? (Hb + (long)grow * 512 + c * 32 + ssg2 * 8) : zbuf;
            gload16(dst + q * 1024, src);
        }
    };

    f32x4 acc[4][4] = {};
    int abuf = 0, bbuf = 0;
    stageB(0, 0);
    stageA(0, 0, 0);
    for (int c = 0; c < 4; ++c) {
        for (int t = 0; t < taps; ++t) {
            if (t + 1 < taps) {
                stageA(abuf ^ 1, c, t + 1);
                asm volatile("s_waitcnt vmcnt(2)" ::: "memory");
            } else if (c + 1 < 4) {
                stageB(bbuf ^ 1, c + 1);
                stageA(abuf ^ 1, c + 1, 0);
                asm volatile("s_waitcnt vmcnt(5)" ::: "memory");
            } else {
                asm volatile("s_waitcnt vmcnt(0)" ::: "memory");
            }
            __builtin_amdgcn_s_barrier();
            __builtin_amdgcn_sched_barrier(0);
            const char* Al = Alds + abuf * 8192;
            const char* Bl = Blds + bbuf * 12288;
            const int shift2 = t - pad + 32;
            s16x8 af[4], bf[4];
            #pragma unroll
            for (int f = 0; f < 4; ++f) {
                int arow = wi + f * 16 + lr;
                af[f] = *(const s16x8*)(Al + arow * 64 + (lg ^ ((arow >> 1) & 3)) * 16);
                int brow = wj + f * 16 + lr + shift2;
                bf[f] = *(const s16x8*)(Bl + brow * 64 + (lg ^ ((brow >> 1) & 3)) * 16);
            }
            __builtin_amdgcn_s_setprio(1);
            #pragma unroll
            for (int fi = 0; fi < 4; ++fi)
                #pragma unroll
                for (int fj = 0; fj < 4; ++fj)
                    acc[fi][fj] = __builtin_amdgcn_mfma_f32_16x16x32_bf16(af[fi], bf[fj], acc[fi][fj], 0, 0, 0);
            __builtin_amdgcn_s_setprio(0);
            __builtin_amdgcn_sched_barrier(0);
            __builtin_amdgcn_s_barrier();
            abuf ^= 1;
            if (t == taps - 1) bbuf ^= 1;
        }
    }
    u16* Db = Y + bb * 524288 + 128 * br;
    #pragma unroll
    for (int fi = 0; fi < 4; ++fi) {
        const int i = wi + fi * 16 + lg * 4;
        #pragma unroll
        for (int fj = 0; fj < 4; ++fj) {
            const int j = j0 + wj + fj * 16 + lr;
            f32x4 d = acc[fi][fj];
            s16x4 o;
            o[0] = (short)f2bf(d[0]); o[1] = (short)f2bf(d[1]);
            o[2] = (short)f2bf(d[2]); o[3] = (short)f2bf(d[3]);
            *(s16x4*)(Db + (long)j * 512 + i) = o;
        }
    }
    // ---- BN partial stats ----
    float sv[16], qv[16];
    #pragma unroll
    for (int fi = 0; fi < 4; ++fi)
        #pragma unroll
        for (int e = 0; e < 4; ++e) {
            float s = 0.f, q = 0.f;
            #pragma unroll
            for (int fj = 0; fj < 4; ++fj) { float d = acc[fi][fj][e]; s += d; q += d * d; }
            sv[fi * 4 + e] = s; qv[fi * 4 + e] = q;
        }
    #pragma unroll
    for (int m = 1; m < 16; m <<= 1) {
        #pragma unroll
        for (int r = 0; r < 16; ++r) {
            sv[r] += __shfl_xor(sv[r], m, 64);
            qv[r] += __shfl_xor(qv[r], m, 64);
        }
    }
    __syncthreads();
    if (lr == 0) {
        #pragma unroll
        for (int r = 0; r < 16; ++r) {
            int co = wi + (r >> 2) * 16 + lg * 4 + (r & 3);
            sred[w & 1][co] = sv[r];
            qred[w & 1][co] = qv[r];
        }
    }
    __syncthreads();
    if (tid < 128) {
        long blk = (long)br * 512 + bb * 8 + jblk;
        part[blk * 256 + tid]       = sred[0][tid] + sred[1][tid];
        part[blk * 256 + 128 + tid] = qred[0][tid] + qred[1][tid];
    }
}

// ================= PD+PL combined GEMM (pure; Y already BN'd), depth-2 =================
__global__ __launch_bounds__(256) void gemm_psl_k(
    const u16* __restrict__ Ybn,
    const u16* __restrict__ Bmat,
    u16* __restrict__ PSL)
{
    __shared__ s16x8 As[2 * 512];
    __shared__ s16x8 Bs[2 * 512];
    int flat = blockIdx.x + 8 * (blockIdx.y + 8 * blockIdx.z);
    int swz = (flat & 7) * 512 + (flat >> 3);
    const int j0 = (swz & 7) * 128;
    const int i0 = ((swz >> 3) & 7) * 128;
    const long bb = swz >> 6;
    const int tid = threadIdx.x;
    const u16* Ab = Ybn + bb * 524288;
    const int srow = tid >> 2, sg = tid & 3;
    const int ssg = sg ^ ((srow >> 1) & 3);
    const int l = tid & 63, w = tid >> 6;
    const int wi = (w >> 1) * 64, wj = (w & 1) * 64;
    const int lr = l & 15, lg = l >> 4;
    const long aoff0 = (long)(i0 + srow) * 512 + ssg * 8;
    const long aoff1 = (long)(i0 + srow + 64) * 512 + ssg * 8;
    const long boff0 = (long)(j0 + srow) * 512 + ssg * 8;
    const long boff1 = (long)(j0 + srow + 64) * 512 + ssg * 8;
    const int nt = 16;
    auto stage = [&](int buf, int t) {
        const int k0 = t << 5;
        char* a0 = (char*)As + buf * 8192 + w * 1024;
        char* b0 = (char*)Bs + buf * 8192 + w * 1024;
        gload16(a0, Ab + aoff0 + k0);
        gload16(a0 + 4096, Ab + aoff1 + k0);
        gload16(b0, Bmat + boff0 + k0);
        gload16(b0 + 4096, Bmat + boff1 + k0);
    };
    f32x4 acc[4][4] = {};
    stage(0, 0);
    for (int t = 0; t < nt; ++t) {
        const int cur = t & 1;
        if (t + 1 < nt) stage(cur ^ 1, t + 1);
        pipe_wait2(t, nt);
        s16x8 af[4], bf[4];
        #pragma unroll
        for (int f = 0; f < 4; ++f) {
            af[f] = As[cur * 512 + lds_chunk(wi + f * 16 + lr, lg)];
            bf[f] = Bs[cur * 512 + lds_chunk(wj + f * 16 + lr, lg)];
        }
        __builtin_amdgcn_s_setprio(1);
        #pragma unroll
        for (int fi = 0; fi < 4; ++fi)
            #pragma unroll
            for (int fj = 0; fj < 4; ++fj)
                acc[fi][fj] = __builtin_amdgcn_mfma_f32_16x16x32_bf16(af[fi], bf[fj], acc[fi][fj], 0, 0, 0);
        __builtin_amdgcn_s_setprio(0);
        pipe_endbar();
    }
    u16* Db = PSL + bb * 1048576;
    #pragma unroll
    for (int fi = 0; fi < 4; ++fi) {
        const int i = i0 + wi + fi * 16 + lg * 4;
        #pragma unroll
        for (int fj = 0; fj < 4; ++fj) {
            const int j = j0 + wj + fj * 16 + lr;
            f32x4 d = acc[fi][fj];
            s16x4 o;
            o[0] = (short)f2bf(d[0]); o[1] = (short)f2bf(d[1]);
            o[2] = (short)f2bf(d[2]); o[3] = (short)f2bf(d[3]);
            *(s16x4*)(Db + (long)j * 1024 + i) = o;
        }
    }
}

// ================= time-axis GEMM: out = MS.PD^T + PL + b2 + x (depth-3) =================
__global__ __launch_bounds__(256) void gemm_time_k(
    const u16* __restrict__ MS,
    const u16* __restrict__ PSL,
    const float* __restrict__ b2, const float* __restrict__ X,
    float* __restrict__ OUT)
{
    __shared__ s16x8 As[3 * 512];
    __shared__ s16x8 Bs[3 * 512];
    int flat = blockIdx.x + 4 * (blockIdx.y + 8 * blockIdx.z);
    int swz = (flat & 7) * 256 + (flat >> 3);
    const int j0 = (swz & 3) * 128;          // co tile
    const int i0 = ((swz >> 2) & 7) * 128;   // n tile
    const long bb = swz >> 5;
    const int tid = threadIdx.x;
    const int srow = tid >> 2, sg = tid & 3;
    const int ssg = sg ^ ((srow >> 1) & 3);
    const int l = tid & 63, w = tid >> 6;
    const int wi = (w >> 1) * 64, wj = (w & 1) * 64;
    const int lr = l & 15, lg = l >> 4;
    const int klo = (i0 - 32) > 0 ? (i0 - 32) : 0;
    const int khi = (i0 + 160) < 1024 ? (i0 + 160) : 1024;
    const int nt = (khi - klo) >> 5;   // 5 or 6
    const u16* B = PSL + bb * 1048576; // PD rows [0,512)
    auto stage = [&](int buf, int t) {
        const int k0 = klo + (t << 5);
        char* a0 = (char*)As + buf * 8192 + w * 1024;
        char* b0 = (char*)Bs + buf * 8192 + w * 1024;
        gload16(a0, MS + (long)(i0 + srow) * 1024 + k0 + ssg * 8);
        gload16(a0 + 4096, MS + (long)(i0 + srow + 64) * 1024 + k0 + ssg * 8);
        gload16(b0, B + (long)(j0 + srow) * 1024 + k0 + ssg * 8);
        gload16(b0 + 4096, B + (long)(j0 + srow + 64) * 1024 + k0 + ssg * 8);
    };
    f32x4 acc[4][4] = {};
    stage(0, 0);
    stage(1, 1);
    int cur = 0;
    for (int t = 0; t < nt; ++t) {
        if (t + 2 < nt) stage((cur + 2) % 3, t + 2);
        pipe_wait3(t, nt);
        s16x8 af[4], bf[4];
        #pragma unroll
        for (int f = 0; f < 4; ++f) {
            af[f] = As[cur * 512 + lds_chunk(wi + f * 16 + lr, lg)];
            bf[f] = Bs[cur * 512 + lds_chunk(wj + f * 16 + lr, lg)];
        }
        __builtin_amdgcn_s_setprio(1);
        #pragma unroll
        for (int fi = 0; fi < 4; ++fi)
            #pragma unroll
            for (int fj = 0; fj < 4; ++fj)
                acc[fi][fj] = __builtin_amdgcn_mfma_f32_16x16x32_bf16(af[fi], bf[fj], acc[fi][fj], 0, 0, 0);
        __builtin_amdgcn_s_setprio(0);
        pipe_endbar();
        cur = (cur + 1) % 3;
    }
    float* Ob = OUT + bb * 524288;
    const float* Xb = X + bb * 524288;
    const u16* PLb = PSL + bb * 1048576 + 524288;   // PL rows [512,1024)
    #pragma unroll
    for (int fi = 0; fi < 4; ++fi) {
        const int i = i0 + wi + fi * 16 + lg * 4;
        #pragma unroll
        for (int fj = 0; fj < 4; ++fj) {
            const int j = j0 + wj + fj * 16 + lr;
            const long a = (long)j * 1024 + i;
            f32x4 d = acc[fi][fj];
            const float bj = b2[j];
            f32x4 xv = *(const f32x4*)(Xb + a);
            s16x4 pl4 = *(const s16x4*)(PLb + a);
            f32x4 o;
            o[0] = d[0] + bj + xv[0] + bf2f((u16)pl4[0]);
            o[1] = d[1] + bj + xv[1] + bf2f((u16)pl4[1]);
            o[2] = d[2] + bj + xv[2] + bf2f((u16)pl4[2]);
            o[3] = d[3] + bj + xv[3] + bf2f((u16)pl4[3]);
            *(f32x4*)(Ob + a) = o;
        }
    }
}

// ================= build wavelet operator MS =================
__global__ __launch_bounds__(256) void build_M_k(u16* __restrict__ MS)
{
    __shared__ float a1[515], d1[515], a2[261], d2[261], sa1[515];
    const int r = blockIdx.x;
    const int t = threadIdx.x;
    for (int m = t; m < 515; m += 256) {
        float sa = 0.f, sd = 0.f;
        #pragma unroll
        for (int j = 0; j < 8; ++j) {
            int tt = 2 * m + 1 - j;
            tt = (tt < 0) ? (-tt - 1) : tt;
            tt = (tt >= 1024) ? (2047 - tt) : tt;
            if (tt == r) { sa += c_lo[j]; sd += c_hi[j]; }
        }
        a1[m] = sa; d1[m] = sd;
    }
    __syncthreads();
    for (int m = t; m < 261; m += 256) {
        float sa = 0.f, sd = 0.f;
        #pragma unroll
        for (int j = 0; j < 8; ++j) {
            int tt = 2 * m + 1 - j;
            tt = (tt < 0) ? (-tt - 1) : tt;
            tt = (tt >= 515) ? (1029 - tt) : tt;
            float v = a1[tt];
            sa += v * c_lo[j]; sd += v * c_hi[j];
        }
        a2[m] = sa; d2[m] = sd;
    }
    __syncthreads();
    for (int m = t; m < 515; m += 256) {
        float ss = 0.f;
        #pragma unroll
        for (int k = 0; k < 8; ++k) {
            int tt = m + k - 1;
            if (tt & 1) continue;
            int j = tt >> 1;
            if (j < 0 || j >= 261) continue;
            ss += c_hi[k] * d2[j];
        }
        sa1[m] = ss;
    }
    __syncthreads();
    for (int n = t; n < 1024; n += 256) {
        float ss = 0.f;
        #pragma unroll
        for (int k = 0; k < 8; ++k) {
            int tt = n + k - 1;
            if (tt & 1) continue;
            int j = tt >> 1;
            if (j < 0 || j >= 515) continue;
            ss += c_lo[k] * sa1[j] + c_hi[k] * d1[j];
        }
        MS[(long)n * 1024 + r] = f2bf(ss);
    }
}

// ================= packing / small kernels =================
__global__ __launch_bounds__(256) void pack_weights_k(
    const float* __restrict__ wi,
    const float* __restrict__ b1, const float* __restrict__ b2_,
    const float* __restrict__ b3, const float* __restrict__ b4,
    u16* __restrict__ Wi, u16* __restrict__ Wp)
{
    int i = blockIdx.x * 256 + threadIdx.x;
    if (i < 262144) Wi[i] = f2bf(wi[i]);
    if (i < 393216) {
        int base, taps;
        const float* s;
        if (i < 49152)       { base = 0;      taps = 3; s = b1; }
        else if (i < 131072) { base = 49152;  taps = 5; s = b2_; }
        else if (i < 245760) { base = 131072; taps = 7; s = b3; }
        else                 { base = 245760; taps = 9; s = b4; }
        int rem = i - base;
        int stride = taps * 128;
        int co = rem / stride;
        int r2 = rem - co * stride;
        int tap = r2 >> 7, ci = r2 & 127;
        Wp[i] = f2bf(s[(long)(co * 128 + ci) * taps + tap]);
    }
}

// UDUL rows [0,512): UD = USc - ULc; rows [512,1024): ULc  (PD/PL weights)
__global__ __launch_bounds__(256) void make_Ucum_k(
    const float* __restrict__ wf, const float* __restrict__ wp,
    u16* __restrict__ UDUL)
{
    int gid = blockIdx.x * 256 + threadIdx.x;   // 512*128
    int co = gid >> 7, cc = gid & 127;
    float us[4], ul[4];
    #pragma unroll
    for (int b = 0; b < 4; ++b) {
        float s = 0.f, t = 0.f;
        for (int q = 0; q < 128; ++q) {
            float f = wf[(long)co * 512 + b * 128 + q];
            s += f * wp[q * 256 + cc];
            t += f * wp[q * 256 + 128 + cc];
        }
        us[b] = s; ul[b] = t;
    }
    float suf[4], pre[4];
    float acc = 0.f;
    for (int b = 3; b >= 0; --b) { acc += us[b]; suf[b] = acc; }
    acc = 0.f;
    for (int b = 0; b < 4; ++b) { acc += ul[b]; pre[b] = acc; }
    #pragma unroll
    for (int b = 0; b < 4; ++b) {
        UDUL[(long)co * 512 + b * 128 + cc]         = f2bf(suf[b] - pre[b]);
        UDUL[(long)(512 + co) * 512 + b * 128 + cc] = f2bf(pre[b]);
    }
}

__global__ __launch_bounds__(256) void make_bias2_k(
    const float* __restrict__ wf, const float* __restrict__ bpf,
    const float* __restrict__ bfus, float* __restrict__ b2)
{
    int co = blockIdx.x * 256 + threadIdx.x;
    if (co >= 512) return;
    float s = bfus[co];
    for (int j = 0; j < 512; ++j) s += wf[(long)co * 512 + j] * bpf[j & 127];
    b2[co] = s;
}

__global__ __launch_bounds__(256) void zero_k(float* __restrict__ p, int n)
{
    int i = blockIdx.x * 256 + threadIdx.x;
    if (i < n) p[i] = 0.f;
}

// ---------------- transpose: xcl[bb][n][c] = bf16(x[bb][c][n]) ----------------
__global__ __launch_bounds__(256) void trX_k(const float* __restrict__ x, u16* __restrict__ xcl)
{
    __shared__ float sh[32][33];
    const int n0 = blockIdx.x * 32, c0 = blockIdx.y * 32;
    const long bb = blockIdx.z;
    const int tx = threadIdx.x, ty = threadIdx.y;
    const float* xb = x + bb * 524288;
    u16* ob = xcl + bb * 524288;
    #pragma unroll
    for (int k = 0; k < 4; ++k)
        sh[ty + 8 * k][tx] = xb[(long)(c0 + ty + 8 * k) * 1024 + n0 + tx];
    __syncthreads();
    #pragma unroll
    for (int k = 0; k < 4; ++k)
        ob[(long)(n0 + ty + 8 * k) * 512 + c0 + tx] = f2bf(sh[tx][ty + 8 * k]);
}

// ---------------- BN ----------------
// one block per channel: tree-reduce 512 partials
__global__ __launch_bounds__(256) void bn_coef_k(
    const float* __restrict__ part, PtrQuad g, PtrQuad be, float* __restrict__ scsh)
{
    __shared__ float rs[256], rq[256];
    int c = blockIdx.x;              // 0..511
    int br = c >> 7, cc = c & 127;
    const float* pb = part + (long)br * 131072;
    int t = threadIdx.x;
    float s = pb[(2 * t) * 256 + cc]       + pb[(2 * t + 1) * 256 + cc];
    float q = pb[(2 * t) * 256 + 128 + cc] + pb[(2 * t + 1) * 256 + 128 + cc];
    rs[t] = s; rq[t] = q;
    __syncthreads();
    for (int off = 128; off > 0; off >>= 1) {
        if (t < off) { rs[t] += rs[t + off]; rq[t] += rq[t + off]; }
        __syncthreads();
    }
    if (t == 0) {
        float mu = rs[0] * (1.0f / 65536.0f);
        float var = rq[0] * (1.0f / 65536.0f) - mu * mu;
        float sc = g.p[br][cc] * rsqrtf(var + 1e-5f);
        scsh[c] = sc;
        scsh[512 + c] = be.p[br][cc] - mu * sc;
    }
}

__global__ __launch_bounds__(256) void bn_apply_k(
    u16* __restrict__ Y, const float* __restrict__ scsh)
{
    __shared__ float sc_[512];
    __shared__ float sh_[512];
    const int t = threadIdx.x;
    #pragma unroll
    for (int q = 0; q < 2; ++q) {
        sc_[t + q * 256] = scsh[t + q * 256];
        sh_[t + q * 256] = scsh[512 + t + q * 256];
    }
    __syncthreads();
    long gid = (long)blockIdx.x * 256 + t;
    long r = gid >> 6; int cg = (int)(gid & 63);
    u16* p = Y + r * 512 + cg * 8;
    s16x8 v = *(const s16x8*)p;
    #pragma unroll
    for (int e = 0; e < 8; ++e) {
        int c = cg * 8 + e;
        float f = bf2f((u16)v[e]) * sc_[c] + sh_[c];
        v[e] = (short)f2bf(f > 0.f ? f : 0.f);
    }
    *(s16x8*)p = v;
}

// =====================================================================
extern "C" void kernel_launch(void* const* d_in, const int* in_sizes, int n_in,
                              void* d_out, int out_size, void* d_ws, size_t ws_size,
                              hipStream_t stream)
{
    const float* x      = (const float*)d_in[0];
    const float* w_init = (const float*)d_in[1];
    const float* b_init = (const float*)d_in[2];
    const float* w_pf   = (const float*)d_in[3];
    const float* b_pf   = (const float*)d_in[4];
    const float* w_fus  = (const float*)d_in[5];
    const float* b_fus  = (const float*)d_in[6];
    const float *w_b[4];
    PtrQuad g, be;
    for (int i = 0; i < 4; ++i) {
        w_b[i]  = (const float*)d_in[7 + 4 * i];
        g.p[i]  = (const float*)d_in[9 + 4 * i];
        be.p[i] = (const float*)d_in[10 + 4 * i];
    }
    float* outf = (float*)d_out;

    char* p = (char*)d_ws;
    u16* xcl   = (u16*)p;  p += 67108864;
    u16* h     = (u16*)p;  p += 67108864;
    u16* Y     = (u16*)p;  p += 67108864;
    u16* PSL   = (u16*)p;  p += 134217728;
    u16* Wi    = (u16*)p;  p += 524288;
    u16* Wp    = (u16*)p;  p += 786432;
    u16* UDUL  = (u16*)p;  p += 1048576;
    u16* MrowS = (u16*)p;  p += 2097152;
    float* b2  = (float*)p; p += 2048;
    float* zbuf= (float*)p; p += 256;     // 64 floats, zeroed each launch
    float* scsh= (float*)p; p += 4096;
    float* part= (float*)p; p += 2097152; // 2048 blocks * 256 floats

    // ---- prologue: weights / operators ----
    pack_weights_k<<<1536, 256, 0, stream>>>(w_init, w_b[0], w_b[1], w_b[2], w_b[3], Wi, Wp);
    make_Ucum_k<<<256, 256, 0, stream>>>(w_fus, w_pf, UDUL);
    make_bias2_k<<<2, 256, 0, stream>>>(w_fus, b_pf, b_fus, b2);
    build_M_k<<<1024, 256, 0, stream>>>(MrowS);
    zero_k<<<1, 256, 0, stream>>>(zbuf, 64);

    // ---- activations: transpose to channel-last bf16 ----
    trX_k<<<dim3(32, 16, 64), dim3(32, 8), 0, stream>>>(x, xcl);

    // ---- conv1x1: h[n][co] = Wi x + b_init ----
    gemm_nt_k<<<dim3(8, 4, 64), 256, 0, stream>>>(Wi, 0, 512, xcl, 524288, 512, 512,
                                                  h, 524288, 512, b_init);

    // ---- branches: chunk-major conv + fused BN partials ----
    gemm_branch4_k<<<dim3(8, 4, 64), 256, 0, stream>>>(Wp, h, Y, (const u16*)zbuf, part);

    // ---- BN coefficients (parallel reduce) + apply (in place) ----
    bn_coef_k<<<512, 256, 0, stream>>>(part, g, be, scsh);
    bn_apply_k<<<16384, 256, 0, stream>>>(Y, scsh);

    // ---- PSL = Ybn . [UD;UL]^T (one launch) ----
    gemm_psl_k<<<dim3(8, 8, 64), 256, 0, stream>>>(Y, UDUL, PSL);

    // ---- out = MS.PD^T + PL + b2 + x ----
    gemm_time_k<<<dim3(4, 8, 64), 256, 0, stream>>>(MrowS, PSL, b2, x, outf);
}